// Round 15
// baseline (1229.154 us; speedup 1.0000x reference)
//
#include <hip/hip_runtime.h>
#include <hip/hip_bf16.h>

#define NN 50000
#define NE 800000
#define DH 128
#define NCLS 40
#define HOPS 30

typedef unsigned int uint32;
typedef unsigned long long uint64;
typedef unsigned short ushort16;
typedef __attribute__((ext_vector_type(8))) short short8v;   // 8 bf16 = 4 VGPR
typedef __attribute__((ext_vector_type(4))) float float4v;   // MFMA acc

// ---------------- helpers ----------------

__device__ __forceinline__ ushort16 bfbits(float x) {
    __hip_bfloat16 b = __float2bfloat16(x);
    return *reinterpret_cast<ushort16*>(&b);
}

__device__ __forceinline__ void unpack8(uint4 u, float* f) {
    f[0] = __uint_as_float(u.x << 16);
    f[1] = __uint_as_float(u.x & 0xffff0000u);
    f[2] = __uint_as_float(u.y << 16);
    f[3] = __uint_as_float(u.y & 0xffff0000u);
    f[4] = __uint_as_float(u.z << 16);
    f[5] = __uint_as_float(u.z & 0xffff0000u);
    f[6] = __uint_as_float(u.w << 16);
    f[7] = __uint_as_float(u.w & 0xffff0000u);
}

__device__ __forceinline__ uint32 pack2(float a, float b) {
    return (uint32)bfbits(a) | ((uint32)bfbits(b) << 16);
}

// csr entry packed in u64: low 32 = src node, high 32 = weight bits
__device__ __forceinline__ int csr_src_of(uint64 c) { return (int)(c & 0xffffffffull); }
__device__ __forceinline__ float csr_w_of(uint64 c) {
    return __uint_as_float((uint32)(c >> 32));
}

// ---------------- graph build ----------------

__global__ void count_deg(const int* __restrict__ dst, int* __restrict__ cnt) {
    int e = blockIdx.x * blockDim.x + threadIdx.x;
    if (e < NE) atomicAdd(&cnt[dst[e]], 1);
}

__global__ void calc_dinv(const int* __restrict__ cnt, float* __restrict__ dinv) {
    int v = blockIdx.x * blockDim.x + threadIdx.x;
    if (v < NN) dinv[v] = rsqrtf((float)cnt[v] + 1.0f);  // +1 self-loop
}

__global__ void scan1(const int* __restrict__ cnt, int* __restrict__ rowptr,
                      int* __restrict__ bsum) {
    __shared__ int s[1024];
    int t = threadIdx.x;
    int i = blockIdx.x * 1024 + t;
    int v = (i < NN) ? cnt[i] : 0;
    s[t] = v;
    __syncthreads();
    for (int off = 1; off < 1024; off <<= 1) {
        int add = (t >= off) ? s[t - off] : 0;
        __syncthreads();
        s[t] += add;
        __syncthreads();
    }
    if (i < NN) rowptr[i] = s[t] - v;
    if (t == 1023) bsum[blockIdx.x] = s[1023];
}

__global__ void scan2(int* __restrict__ bsum, int* __restrict__ rowptr, int nb) {
    if (blockIdx.x == 0 && threadIdx.x == 0) {
        int run = 0;
        for (int b = 0; b < nb; ++b) { int v = bsum[b]; bsum[b] = run; run += v; }
        rowptr[NN] = run;
    }
}

__global__ void scan3(int* __restrict__ rowptr, const int* __restrict__ bsum,
                      int* __restrict__ cursor) {
    int i = blockIdx.x * 1024 + threadIdx.x;
    if (i < NN) {
        int r = rowptr[i] + bsum[blockIdx.x];
        rowptr[i] = r;
        cursor[i] = r;
    }
}

// csr u64: low=src, high=weight bits (dinv[s]*dinv[d])
__global__ void fill_csr(const int* __restrict__ src, const int* __restrict__ dst,
                         const float* __restrict__ dinv, int* __restrict__ cursor,
                         uint64* __restrict__ csr) {
    int e = blockIdx.x * blockDim.x + threadIdx.x;
    if (e < NE) {
        int s = src[e], d = dst[e];
        int p = atomicAdd(&cursor[d], 1);
        uint64 val = (uint64)(uint32)s |
                     ((uint64)__float_as_uint(dinv[s] * dinv[d]) << 32);
        __builtin_nontemporal_store(val, csr + p);
    }
}

// ---------------- weight prep ----------------

__global__ void prep_wt(const float* __restrict__ W1, const float* __restrict__ W2,
                        ushort16* __restrict__ w1t, ushort16* __restrict__ w2t) {
    int i = blockIdx.x * 256 + threadIdx.x;   // 0..32767
    if (i < 16384) {
        int n = i >> 7, k = i & 127;
        w1t[n * 128 + k] = bfbits(W1[k * 128 + n]);
    } else {
        int j = i - 16384;
        int n = j >> 7, k = j & 127;
        w2t[n * 128 + k] = bfbits(W2[k * 128 + n]);
    }
}

__global__ void prep_wc(const float* __restrict__ Wc, ushort16* __restrict__ wct) {
    int i = blockIdx.x * 256 + threadIdx.x;   // 48*128 = 6144
    if (i < 48 * 128) {
        int n = i >> 7, k = i & 127;
        wct[i] = (n < NCLS) ? bfbits(Wc[k * NCLS + n]) : (ushort16)0;
    }
}

// ---------------- conv GEMM via bf16 MFMA (16x16x32) ----------------

template <bool AF32, bool RELU>
__global__ __launch_bounds__(256) void conv_mfma(const void* __restrict__ Ap,
                                                 const ushort16* __restrict__ WT,
                                                 const float* __restrict__ bias,
                                                 ushort16* __restrict__ C) {
    const int t = threadIdx.x;
    const int w = t >> 6;          // wave 0..3
    const int l = t & 63;
    const int rb = blockIdx.x * 128 + w * 32;
    const int lr = l & 15;
    const int lk = (l >> 4) * 8;

    short8v afr[2][4];
#pragma unroll
    for (int rt = 0; rt < 2; ++rt) {
        int row = rb + rt * 16 + lr;
        if (row > NN - 1) row = NN - 1;   // clamp (stores are guarded)
#pragma unroll
        for (int ks = 0; ks < 4; ++ks) {
            int k0 = ks * 32 + lk;
            if (AF32) {
                const float* ap = (const float*)Ap + (size_t)row * 128 + k0;
                float4 f0 = *(const float4*)ap;
                float4 f1 = *(const float4*)(ap + 4);
                short8v s;
                s[0] = (short)bfbits(f0.x); s[1] = (short)bfbits(f0.y);
                s[2] = (short)bfbits(f0.z); s[3] = (short)bfbits(f0.w);
                s[4] = (short)bfbits(f1.x); s[5] = (short)bfbits(f1.y);
                s[6] = (short)bfbits(f1.z); s[7] = (short)bfbits(f1.w);
                afr[rt][ks] = s;
            } else {
                afr[rt][ks] = *(const short8v*)((const ushort16*)Ap +
                                                (size_t)row * 128 + k0);
            }
        }
    }

    float4v acc[2][8];
#pragma unroll
    for (int rt = 0; rt < 2; ++rt)
#pragma unroll
        for (int ct = 0; ct < 8; ++ct)
            acc[rt][ct] = (float4v){0.f, 0.f, 0.f, 0.f};

#pragma unroll
    for (int ks = 0; ks < 4; ++ks) {
        short8v bfr[8];
#pragma unroll
        for (int ct = 0; ct < 8; ++ct)
            bfr[ct] = *(const short8v*)(WT + (size_t)(ct * 16 + lr) * 128 +
                                        ks * 32 + lk);
#pragma unroll
        for (int ct = 0; ct < 8; ++ct) {
            acc[0][ct] = __builtin_amdgcn_mfma_f32_16x16x32_bf16(
                afr[0][ks], bfr[ct], acc[0][ct], 0, 0, 0);
            acc[1][ct] = __builtin_amdgcn_mfma_f32_16x16x32_bf16(
                afr[1][ks], bfr[ct], acc[1][ct], 0, 0, 0);
        }
    }

    // epilogue: C/D layout col=lane&15, row=(lane>>4)*4+r  [m89]
#pragma unroll
    for (int ct = 0; ct < 8; ++ct) {
        int col = ct * 16 + lr;
        float bv = bias[col];
#pragma unroll
        for (int rt = 0; rt < 2; ++rt) {
#pragma unroll
            for (int r = 0; r < 4; ++r) {
                int row = rb + rt * 16 + (l >> 4) * 4 + r;
                if (row < NN) {
                    float o = acc[rt][ct][r] + bv;
                    if (RELU) o = fmaxf(o, 0.f);
                    C[(size_t)row * 128 + col] = bfbits(o);
                }
            }
        }
    }
}

// ---------------- classifier via bf16 MFMA (48 padded cols) ----------------

__global__ __launch_bounds__(256) void cls_mfma(const ushort16* __restrict__ q,
                                                const ushort16* __restrict__ WcT,
                                                const float* __restrict__ bc,
                                                const float* __restrict__ psum,
                                                float* __restrict__ out) {
    const int t = threadIdx.x;
    const int w = t >> 6;
    const int l = t & 63;
    const int rb = blockIdx.x * 128 + w * 32;
    const int lr = l & 15;
    const int lk = (l >> 4) * 8;

    short8v afr[2][4];
#pragma unroll
    for (int rt = 0; rt < 2; ++rt) {
        int row = rb + rt * 16 + lr;
        if (row > NN - 1) row = NN - 1;
#pragma unroll
        for (int ks = 0; ks < 4; ++ks)
            afr[rt][ks] = *(const short8v*)(q + (size_t)row * 128 + ks * 32 + lk);
    }

    float4v acc[2][3];
#pragma unroll
    for (int rt = 0; rt < 2; ++rt)
#pragma unroll
        for (int ct = 0; ct < 3; ++ct)
            acc[rt][ct] = (float4v){0.f, 0.f, 0.f, 0.f};

#pragma unroll
    for (int ks = 0; ks < 4; ++ks) {
        short8v bfr[3];
#pragma unroll
        for (int ct = 0; ct < 3; ++ct)
            bfr[ct] = *(const short8v*)(WcT + (size_t)(ct * 16 + lr) * 128 +
                                        ks * 32 + lk);
#pragma unroll
        for (int ct = 0; ct < 3; ++ct) {
            acc[0][ct] = __builtin_amdgcn_mfma_f32_16x16x32_bf16(
                afr[0][ks], bfr[ct], acc[0][ct], 0, 0, 0);
            acc[1][ct] = __builtin_amdgcn_mfma_f32_16x16x32_bf16(
                afr[1][ks], bfr[ct], acc[1][ct], 0, 0, 0);
        }
    }

#pragma unroll
    for (int rt = 0; rt < 2; ++rt) {
#pragma unroll
        for (int r = 0; r < 4; ++r) {
            int row = rb + rt * 16 + (l >> 4) * 4 + r;
            if (row < NN) {
                float pv = psum[row];
#pragma unroll
                for (int ct = 0; ct < 3; ++ct) {
                    int col = ct * 16 + lr;
                    if (col < NCLS)
                        out[(size_t)row * NCLS + col] =
                            acc[rt][ct][r] + pv * bc[col];
                }
            }
        }
    }
}

// ---------------- propagation: 16 lanes/node, 8-edge unroll, NT csr stream ----------------
// One gather instruction serves 4 nodes (64 lanes x 16B = 1KB).

__global__ __launch_bounds__(256) void prop16(const uint4* __restrict__ hin,
                                              uint4* __restrict__ hout,
                                              const int* __restrict__ rowptr,
                                              const uint64* __restrict__ csr,
                                              const float* __restrict__ dinv,
                                              float* __restrict__ psum,
                                              int relu, int wpsum) {
    const int v = blockIdx.x * 16 + (threadIdx.x >> 4);
    const int l = threadIdx.x & 15;
    if (v >= NN) return;

    const float dv = dinv[v];
    const float wself = dv * dv;
    float accp = wself;

    float acc[8];
    {
        float f[8];
        unpack8(hin[(size_t)v * 16 + l], f);
#pragma unroll
        for (int j = 0; j < 8; ++j) acc[j] = wself * f[j];
    }

    int e = rowptr[v];
    const int end = rowptr[v + 1];

    for (; e + 8 <= end; e += 8) {
        uint64 c[8];
        uint4 u[8];
#pragma unroll
        for (int i = 0; i < 8; ++i) c[i] = __builtin_nontemporal_load(csr + e + i);
#pragma unroll
        for (int i = 0; i < 8; ++i) u[i] = hin[(size_t)csr_src_of(c[i]) * 16 + l];
#pragma unroll
        for (int i = 0; i < 8; ++i) {
            float wi = csr_w_of(c[i]);
            accp += wi;
            float fi[8];
            unpack8(u[i], fi);
#pragma unroll
            for (int j = 0; j < 8; ++j) acc[j] += wi * fi[j];
        }
    }
    for (; e + 2 <= end; e += 2) {
        uint64 c0 = __builtin_nontemporal_load(csr + e);
        uint64 c1 = __builtin_nontemporal_load(csr + e + 1);
        uint4 u0 = hin[(size_t)csr_src_of(c0) * 16 + l];
        uint4 u1 = hin[(size_t)csr_src_of(c1) * 16 + l];
        float w0 = csr_w_of(c0);
        float w1 = csr_w_of(c1);
        accp += w0 + w1;
        float f0[8], f1[8];
        unpack8(u0, f0);
        unpack8(u1, f1);
#pragma unroll
        for (int j = 0; j < 8; ++j) acc[j] += w0 * f0[j] + w1 * f1[j];
    }
    if (e < end) {
        uint64 c0 = __builtin_nontemporal_load(csr + e);
        uint4 u0 = hin[(size_t)csr_src_of(c0) * 16 + l];
        float w0 = csr_w_of(c0);
        accp += w0;
        float f0[8];
        unpack8(u0, f0);
#pragma unroll
        for (int j = 0; j < 8; ++j) acc[j] += w0 * f0[j];
    }

    if (relu) {
#pragma unroll
        for (int j = 0; j < 8; ++j) acc[j] = fmaxf(acc[j], 0.f);
    }

    uint4 u;
    u.x = pack2(acc[0], acc[1]);
    u.y = pack2(acc[2], acc[3]);
    u.z = pack2(acc[4], acc[5]);
    u.w = pack2(acc[6], acc[7]);
    hout[(size_t)v * 16 + l] = u;
    if (wpsum && l == 0) psum[v] = accp;
}

// ---------------- launch ----------------

extern "C" void kernel_launch(void* const* d_in, const int* in_sizes, int n_in,
                              void* d_out, int out_size, void* d_ws, size_t ws_size,
                              hipStream_t stream) {
    const float* x   = (const float*)d_in[0];
    const int* edge  = (const int*)d_in[1];
    const float* W1  = (const float*)d_in[2];
    const float* b1  = (const float*)d_in[3];
    const float* W2  = (const float*)d_in[4];
    const float* b2  = (const float*)d_in[5];
    const float* Wc  = (const float*)d_in[6];
    const float* bc  = (const float*)d_in[7];
    // d_in[8] = conv_time (=30), hardcoded as HOPS
    const int* esrc = edge;
    const int* edst = edge + NE;
    float* out = (float*)d_out;

    char* w = (char*)d_ws;
    auto alloc = [&](size_t bytes) { void* p = (void*)w; w += (bytes + 255) & ~(size_t)255; return p; };
    int*      cnt     = (int*)     alloc((size_t)NN * 4);
    float*    dinv    = (float*)   alloc((size_t)NN * 4);
    int*      rowptr  = (int*)     alloc((size_t)(NN + 1) * 4);
    int*      bsum    = (int*)     alloc(64 * 4);
    int*      cursor  = (int*)     alloc((size_t)NN * 4);
    uint64*   csr     = (uint64*)  alloc((size_t)NE * 8);
    ushort16* w1t     = (ushort16*)alloc(128 * 128 * 2);
    ushort16* w2t     = (ushort16*)alloc(128 * 128 * 2);
    ushort16* wct     = (ushort16*)alloc(48 * 128 * 2);
    ushort16* h0b     = (ushort16*)alloc((size_t)NN * DH * 2);   // conv1 out / q
    uint4*    hb0     = (uint4*)   alloc((size_t)NN * DH * 2);   // hop buffers bf16
    uint4*    hb1     = (uint4*)   alloc((size_t)NN * DH * 2);
    float*    psum    = (float*)   alloc((size_t)NN * 4);

    const int NB_SCAN = (NN + 1023) / 1024;  // 49
    const int NCHUNK = (NN + 127) / 128;     // 391

    hipMemsetAsync(cnt, 0, (size_t)NN * 4, stream);
    count_deg<<<(NE + 255) / 256, 256, 0, stream>>>(edst, cnt);
    calc_dinv<<<(NN + 255) / 256, 256, 0, stream>>>(cnt, dinv);
    scan1<<<NB_SCAN, 1024, 0, stream>>>(cnt, rowptr, bsum);
    scan2<<<1, 64, 0, stream>>>(bsum, rowptr, NB_SCAN);
    scan3<<<NB_SCAN, 1024, 0, stream>>>(rowptr, bsum, cursor);
    fill_csr<<<(NE + 255) / 256, 256, 0, stream>>>(esrc, edst, dinv, cursor, csr);
    prep_wt<<<128, 256, 0, stream>>>(W1, W2, w1t, w2t);
    prep_wc<<<24, 256, 0, stream>>>(Wc, wct);

    // conv1: h0b = bf16(relu(x @ W1 + b1))
    conv_mfma<true, true><<<NCHUNK, 256, 0, stream>>>(x, w1t, b1, h0b);
    // conv2: hb0 = bf16(h0b @ W2 + b2)
    conv_mfma<false, false><<<NCHUNK, 256, 0, stream>>>(h0b, w2t, b2,
                                                        (ushort16*)hb0);

    // 30 hops (relu on last), then 31st commuted hop -> q (bf16) + psum
    uint4* cur = hb0;
    uint4* alt = hb1;
    for (int hop = 0; hop < HOPS; ++hop) {
        prop16<<<(NN + 15) / 16, 256, 0, stream>>>(cur, alt, rowptr, csr, dinv,
                                                   psum, (hop == HOPS - 1) ? 1 : 0, 0);
        uint4* tmp = cur; cur = alt; alt = tmp;
    }
    prop16<<<(NN + 15) / 16, 256, 0, stream>>>(cur, (uint4*)h0b, rowptr, csr,
                                               dinv, psum, 0, 1);

    // out = q @ Wc + psum .* bc
    cls_mfma<<<NCHUNK, 256, 0, stream>>>(h0b, wct, bc, psum, out);
}

// Round 16
// 1198.853 us; speedup vs baseline: 1.0253x; 1.0253x over previous
//
#include <hip/hip_runtime.h>
#include <hip/hip_bf16.h>

#define NN 50000
#define NE 800000
#define DH 128
#define NCLS 40
#define HOPS 30

typedef unsigned int uint32;
typedef unsigned short ushort16;
typedef __attribute__((ext_vector_type(8))) short short8v;   // 8 bf16 = 4 VGPR
typedef __attribute__((ext_vector_type(4))) float float4v;   // MFMA acc

// ---------------- helpers ----------------

__device__ __forceinline__ ushort16 bfbits(float x) {
    __hip_bfloat16 b = __float2bfloat16(x);
    return *reinterpret_cast<ushort16*>(&b);
}

__device__ __forceinline__ void unpack8(uint4 u, float* f) {
    f[0] = __uint_as_float(u.x << 16);
    f[1] = __uint_as_float(u.x & 0xffff0000u);
    f[2] = __uint_as_float(u.y << 16);
    f[3] = __uint_as_float(u.y & 0xffff0000u);
    f[4] = __uint_as_float(u.z << 16);
    f[5] = __uint_as_float(u.z & 0xffff0000u);
    f[6] = __uint_as_float(u.w << 16);
    f[7] = __uint_as_float(u.w & 0xffff0000u);
}

__device__ __forceinline__ uint32 pack2(float a, float b) {
    return (uint32)bfbits(a) | ((uint32)bfbits(b) << 16);
}

// ---------------- graph build ----------------

__global__ void count_deg(const int* __restrict__ dst, int* __restrict__ cnt) {
    int e = blockIdx.x * blockDim.x + threadIdx.x;
    if (e < NE) atomicAdd(&cnt[dst[e]], 1);
}

__global__ void calc_dinv(const int* __restrict__ cnt, float* __restrict__ dinv) {
    int v = blockIdx.x * blockDim.x + threadIdx.x;
    if (v < NN) dinv[v] = rsqrtf((float)cnt[v] + 1.0f);  // +1 self-loop
}

__global__ void scan1(const int* __restrict__ cnt, int* __restrict__ rowptr,
                      int* __restrict__ bsum) {
    __shared__ int s[1024];
    int t = threadIdx.x;
    int i = blockIdx.x * 1024 + t;
    int v = (i < NN) ? cnt[i] : 0;
    s[t] = v;
    __syncthreads();
    for (int off = 1; off < 1024; off <<= 1) {
        int add = (t >= off) ? s[t - off] : 0;
        __syncthreads();
        s[t] += add;
        __syncthreads();
    }
    if (i < NN) rowptr[i] = s[t] - v;
    if (t == 1023) bsum[blockIdx.x] = s[1023];
}

__global__ void scan2(int* __restrict__ bsum, int* __restrict__ rowptr, int nb) {
    if (blockIdx.x == 0 && threadIdx.x == 0) {
        int run = 0;
        for (int b = 0; b < nb; ++b) { int v = bsum[b]; bsum[b] = run; run += v; }
        rowptr[NN] = run;
    }
}

__global__ void scan3(int* __restrict__ rowptr, const int* __restrict__ bsum,
                      int* __restrict__ cursor) {
    int i = blockIdx.x * 1024 + threadIdx.x;
    if (i < NN) {
        int r = rowptr[i] + bsum[blockIdx.x];
        rowptr[i] = r;
        cursor[i] = r;
    }
}

// csr packed: .x = src node, .y = weight bits (dinv[s]*dinv[d])
__global__ void fill_csr(const int* __restrict__ src, const int* __restrict__ dst,
                         const float* __restrict__ dinv, int* __restrict__ cursor,
                         int2* __restrict__ csr) {
    int e = blockIdx.x * blockDim.x + threadIdx.x;
    if (e < NE) {
        int s = src[e], d = dst[e];
        int p = atomicAdd(&cursor[d], 1);
        csr[p] = make_int2(s, __float_as_int(dinv[s] * dinv[d]));
    }
}

// ---------------- weight prep ----------------

__global__ void prep_wt(const float* __restrict__ W1, const float* __restrict__ W2,
                        ushort16* __restrict__ w1t, ushort16* __restrict__ w2t) {
    int i = blockIdx.x * 256 + threadIdx.x;   // 0..32767
    if (i < 16384) {
        int n = i >> 7, k = i & 127;
        w1t[n * 128 + k] = bfbits(W1[k * 128 + n]);
    } else {
        int j = i - 16384;
        int n = j >> 7, k = j & 127;
        w2t[n * 128 + k] = bfbits(W2[k * 128 + n]);
    }
}

__global__ void prep_wc(const float* __restrict__ Wc, ushort16* __restrict__ wct) {
    int i = blockIdx.x * 256 + threadIdx.x;   // 48*128 = 6144
    if (i < 48 * 128) {
        int n = i >> 7, k = i & 127;
        wct[i] = (n < NCLS) ? bfbits(Wc[k * NCLS + n]) : (ushort16)0;
    }
}

// ---------------- conv GEMM via bf16 MFMA (16x16x32) ----------------

template <bool AF32, bool RELU>
__global__ __launch_bounds__(256) void conv_mfma(const void* __restrict__ Ap,
                                                 const ushort16* __restrict__ WT,
                                                 const float* __restrict__ bias,
                                                 ushort16* __restrict__ C) {
    const int t = threadIdx.x;
    const int w = t >> 6;          // wave 0..3
    const int l = t & 63;
    const int rb = blockIdx.x * 128 + w * 32;
    const int lr = l & 15;
    const int lk = (l >> 4) * 8;

    short8v afr[2][4];
#pragma unroll
    for (int rt = 0; rt < 2; ++rt) {
        int row = rb + rt * 16 + lr;
        if (row > NN - 1) row = NN - 1;   // clamp (stores are guarded)
#pragma unroll
        for (int ks = 0; ks < 4; ++ks) {
            int k0 = ks * 32 + lk;
            if (AF32) {
                const float* ap = (const float*)Ap + (size_t)row * 128 + k0;
                float4 f0 = *(const float4*)ap;
                float4 f1 = *(const float4*)(ap + 4);
                short8v s;
                s[0] = (short)bfbits(f0.x); s[1] = (short)bfbits(f0.y);
                s[2] = (short)bfbits(f0.z); s[3] = (short)bfbits(f0.w);
                s[4] = (short)bfbits(f1.x); s[5] = (short)bfbits(f1.y);
                s[6] = (short)bfbits(f1.z); s[7] = (short)bfbits(f1.w);
                afr[rt][ks] = s;
            } else {
                afr[rt][ks] = *(const short8v*)((const ushort16*)Ap +
                                                (size_t)row * 128 + k0);
            }
        }
    }

    float4v acc[2][8];
#pragma unroll
    for (int rt = 0; rt < 2; ++rt)
#pragma unroll
        for (int ct = 0; ct < 8; ++ct)
            acc[rt][ct] = (float4v){0.f, 0.f, 0.f, 0.f};

#pragma unroll
    for (int ks = 0; ks < 4; ++ks) {
        short8v bfr[8];
#pragma unroll
        for (int ct = 0; ct < 8; ++ct)
            bfr[ct] = *(const short8v*)(WT + (size_t)(ct * 16 + lr) * 128 +
                                        ks * 32 + lk);
#pragma unroll
        for (int ct = 0; ct < 8; ++ct) {
            acc[0][ct] = __builtin_amdgcn_mfma_f32_16x16x32_bf16(
                afr[0][ks], bfr[ct], acc[0][ct], 0, 0, 0);
            acc[1][ct] = __builtin_amdgcn_mfma_f32_16x16x32_bf16(
                afr[1][ks], bfr[ct], acc[1][ct], 0, 0, 0);
        }
    }

    // epilogue: C/D layout col=lane&15, row=(lane>>4)*4+r  [m89]
#pragma unroll
    for (int ct = 0; ct < 8; ++ct) {
        int col = ct * 16 + lr;
        float bv = bias[col];
#pragma unroll
        for (int rt = 0; rt < 2; ++rt) {
#pragma unroll
            for (int r = 0; r < 4; ++r) {
                int row = rb + rt * 16 + (l >> 4) * 4 + r;
                if (row < NN) {
                    float o = acc[rt][ct][r] + bv;
                    if (RELU) o = fmaxf(o, 0.f);
                    C[(size_t)row * 128 + col] = bfbits(o);
                }
            }
        }
    }
}

// ---------------- classifier via bf16 MFMA (48 padded cols) ----------------

__global__ __launch_bounds__(256) void cls_mfma(const ushort16* __restrict__ q,
                                                const ushort16* __restrict__ WcT,
                                                const float* __restrict__ bc,
                                                const float* __restrict__ psum,
                                                float* __restrict__ out) {
    const int t = threadIdx.x;
    const int w = t >> 6;
    const int l = t & 63;
    const int rb = blockIdx.x * 128 + w * 32;
    const int lr = l & 15;
    const int lk = (l >> 4) * 8;

    short8v afr[2][4];
#pragma unroll
    for (int rt = 0; rt < 2; ++rt) {
        int row = rb + rt * 16 + lr;
        if (row > NN - 1) row = NN - 1;
#pragma unroll
        for (int ks = 0; ks < 4; ++ks)
            afr[rt][ks] = *(const short8v*)(q + (size_t)row * 128 + ks * 32 + lk);
    }

    float4v acc[2][3];
#pragma unroll
    for (int rt = 0; rt < 2; ++rt)
#pragma unroll
        for (int ct = 0; ct < 3; ++ct)
            acc[rt][ct] = (float4v){0.f, 0.f, 0.f, 0.f};

#pragma unroll
    for (int ks = 0; ks < 4; ++ks) {
        short8v bfr[3];
#pragma unroll
        for (int ct = 0; ct < 3; ++ct)
            bfr[ct] = *(const short8v*)(WcT + (size_t)(ct * 16 + lr) * 128 +
                                        ks * 32 + lk);
#pragma unroll
        for (int ct = 0; ct < 3; ++ct) {
            acc[0][ct] = __builtin_amdgcn_mfma_f32_16x16x32_bf16(
                afr[0][ks], bfr[ct], acc[0][ct], 0, 0, 0);
            acc[1][ct] = __builtin_amdgcn_mfma_f32_16x16x32_bf16(
                afr[1][ks], bfr[ct], acc[1][ct], 0, 0, 0);
        }
    }

#pragma unroll
    for (int rt = 0; rt < 2; ++rt) {
#pragma unroll
        for (int r = 0; r < 4; ++r) {
            int row = rb + rt * 16 + (l >> 4) * 4 + r;
            if (row < NN) {
                float pv = psum[row];
#pragma unroll
                for (int ct = 0; ct < 3; ++ct) {
                    int col = ct * 16 + lr;
                    if (col < NCLS)
                        out[(size_t)row * NCLS + col] =
                            acc[rt][ct][r] + pv * bc[col];
                }
            }
        }
    }
}

// ---------------- propagation: 16 lanes/node, 4-edge unroll ----------------
// One gather instruction serves 4 nodes (64 lanes x 16B = 1KB).

__global__ __launch_bounds__(256) void prop16(const uint4* __restrict__ hin,
                                              uint4* __restrict__ hout,
                                              const int* __restrict__ rowptr,
                                              const int2* __restrict__ csr,
                                              const float* __restrict__ dinv,
                                              float* __restrict__ psum,
                                              int relu, int wpsum) {
    const int v = blockIdx.x * 16 + (threadIdx.x >> 4);
    const int l = threadIdx.x & 15;
    if (v >= NN) return;

    const float dv = dinv[v];
    const float wself = dv * dv;
    float accp = wself;

    float acc[8];
    {
        float f[8];
        unpack8(hin[(size_t)v * 16 + l], f);
#pragma unroll
        for (int j = 0; j < 8; ++j) acc[j] = wself * f[j];
    }

    int e = rowptr[v];
    const int end = rowptr[v + 1];
    for (; e + 4 <= end; e += 4) {
        int2 c0 = csr[e];
        int2 c1 = csr[e + 1];
        int2 c2 = csr[e + 2];
        int2 c3 = csr[e + 3];
        uint4 u0 = hin[(size_t)c0.x * 16 + l];
        uint4 u1 = hin[(size_t)c1.x * 16 + l];
        uint4 u2 = hin[(size_t)c2.x * 16 + l];
        uint4 u3 = hin[(size_t)c3.x * 16 + l];
        float w0 = __int_as_float(c0.y);
        float w1 = __int_as_float(c1.y);
        float w2 = __int_as_float(c2.y);
        float w3 = __int_as_float(c3.y);
        accp += (w0 + w1) + (w2 + w3);
        float f0[8], f1[8], f2[8], f3[8];
        unpack8(u0, f0);
        unpack8(u1, f1);
        unpack8(u2, f2);
        unpack8(u3, f3);
#pragma unroll
        for (int j = 0; j < 8; ++j)
            acc[j] += (w0 * f0[j] + w1 * f1[j]) + (w2 * f2[j] + w3 * f3[j]);
    }
    for (; e < end; ++e) {
        int2 c0 = csr[e];
        uint4 u0 = hin[(size_t)c0.x * 16 + l];
        float w0 = __int_as_float(c0.y);
        accp += w0;
        float f0[8];
        unpack8(u0, f0);
#pragma unroll
        for (int j = 0; j < 8; ++j) acc[j] += w0 * f0[j];
    }

    if (relu) {
#pragma unroll
        for (int j = 0; j < 8; ++j) acc[j] = fmaxf(acc[j], 0.f);
    }

    uint4 u;
    u.x = pack2(acc[0], acc[1]);
    u.y = pack2(acc[2], acc[3]);
    u.z = pack2(acc[4], acc[5]);
    u.w = pack2(acc[6], acc[7]);
    hout[(size_t)v * 16 + l] = u;
    if (wpsum && l == 0) psum[v] = accp;
}

// ---------------- launch ----------------

extern "C" void kernel_launch(void* const* d_in, const int* in_sizes, int n_in,
                              void* d_out, int out_size, void* d_ws, size_t ws_size,
                              hipStream_t stream) {
    const float* x   = (const float*)d_in[0];
    const int* edge  = (const int*)d_in[1];
    const float* W1  = (const float*)d_in[2];
    const float* b1  = (const float*)d_in[3];
    const float* W2  = (const float*)d_in[4];
    const float* b2  = (const float*)d_in[5];
    const float* Wc  = (const float*)d_in[6];
    const float* bc  = (const float*)d_in[7];
    // d_in[8] = conv_time (=30), hardcoded as HOPS
    const int* esrc = edge;
    const int* edst = edge + NE;
    float* out = (float*)d_out;

    char* w = (char*)d_ws;
    auto alloc = [&](size_t bytes) { void* p = (void*)w; w += (bytes + 255) & ~(size_t)255; return p; };
    int*      cnt     = (int*)     alloc((size_t)NN * 4);
    float*    dinv    = (float*)   alloc((size_t)NN * 4);
    int*      rowptr  = (int*)     alloc((size_t)(NN + 1) * 4);
    int*      bsum    = (int*)     alloc(64 * 4);
    int*      cursor  = (int*)     alloc((size_t)NN * 4);
    int2*     csr     = (int2*)    alloc((size_t)NE * 8);
    ushort16* w1t     = (ushort16*)alloc(128 * 128 * 2);
    ushort16* w2t     = (ushort16*)alloc(128 * 128 * 2);
    ushort16* wct     = (ushort16*)alloc(48 * 128 * 2);
    ushort16* h0b     = (ushort16*)alloc((size_t)NN * DH * 2);   // conv1 out / q
    uint4*    hb0     = (uint4*)   alloc((size_t)NN * DH * 2);   // hop buffers bf16
    uint4*    hb1     = (uint4*)   alloc((size_t)NN * DH * 2);
    float*    psum    = (float*)   alloc((size_t)NN * 4);

    const int NB_SCAN = (NN + 1023) / 1024;  // 49
    const int NCHUNK = (NN + 127) / 128;     // 391

    hipMemsetAsync(cnt, 0, (size_t)NN * 4, stream);
    count_deg<<<(NE + 255) / 256, 256, 0, stream>>>(edst, cnt);
    calc_dinv<<<(NN + 255) / 256, 256, 0, stream>>>(cnt, dinv);
    scan1<<<NB_SCAN, 1024, 0, stream>>>(cnt, rowptr, bsum);
    scan2<<<1, 64, 0, stream>>>(bsum, rowptr, NB_SCAN);
    scan3<<<NB_SCAN, 1024, 0, stream>>>(rowptr, bsum, cursor);
    fill_csr<<<(NE + 255) / 256, 256, 0, stream>>>(esrc, edst, dinv, cursor, csr);
    prep_wt<<<128, 256, 0, stream>>>(W1, W2, w1t, w2t);
    prep_wc<<<24, 256, 0, stream>>>(Wc, wct);

    // conv1: h0b = bf16(relu(x @ W1 + b1))
    conv_mfma<true, true><<<NCHUNK, 256, 0, stream>>>(x, w1t, b1, h0b);
    // conv2: hb0 = bf16(h0b @ W2 + b2)
    conv_mfma<false, false><<<NCHUNK, 256, 0, stream>>>(h0b, w2t, b2,
                                                        (ushort16*)hb0);

    // 30 hops (relu on last), then 31st commuted hop -> q (bf16) + psum
    uint4* cur = hb0;
    uint4* alt = hb1;
    for (int hop = 0; hop < HOPS; ++hop) {
        prop16<<<(NN + 15) / 16, 256, 0, stream>>>(cur, alt, rowptr, csr, dinv,
                                                   psum, (hop == HOPS - 1) ? 1 : 0, 0);
        uint4* tmp = cur; cur = alt; alt = tmp;
    }
    prop16<<<(NN + 15) / 16, 256, 0, stream>>>(cur, (uint4*)h0b, rowptr, csr,
                                               dinv, psum, 0, 1);

    // out = q @ Wc + psum .* bc
    cls_mfma<<<NCHUNK, 256, 0, stream>>>(h0b, wct, bc, psum, out);
}